// Round 7
// baseline (342.451 us; speedup 1.0000x reference)
//
#include <hip/hip_runtime.h>
#include <hip/hip_bf16.h>
#include <stdint.h>

typedef __hip_bfloat16 bf16;
using f32x4 = __attribute__((ext_vector_type(4))) float;
using s16x8 = __attribute__((ext_vector_type(8))) short;

typedef __attribute__((address_space(1))) unsigned int gu32;
typedef __attribute__((address_space(3))) unsigned int lu32;

__device__ __forceinline__ void gll16(const void* g, void* l) {
  __builtin_amdgcn_global_load_lds((const gu32*)g, (lu32*)l, 16, 0, 0);
}

// ---------------- convert f32 -> bf16 ----------------
struct ConvJob { const float* src; bf16* dst; int n4; int pad; };
struct ConvParams { ConvJob j[10]; };
struct alignas(8) Bf4 { bf16 v[4]; };

__global__ void convert_kernel(ConvParams p) {
  ConvJob jb = p.j[blockIdx.z];
  int stride = gridDim.x * blockDim.x;
  for (int i = blockIdx.x * blockDim.x + threadIdx.x; i < jb.n4; i += stride) {
    float4 v = ((const float4*)jb.src)[i];
    Bf4 o;
    o.v[0] = __float2bfloat16(v.x);
    o.v[1] = __float2bfloat16(v.y);
    o.v[2] = __float2bfloat16(v.z);
    o.v[3] = __float2bfloat16(v.w);
    ((Bf4*)jb.dst)[i] = o;
  }
}

// ---------------- GEMM: C = A(MxK) @ W(NxK)^T + bias ----------------
// K-loop: round-1 verified structure (128x128 tile, 256 thr, 4 waves 2x2,
// dbuf 64 KiB, counted vmcnt(8), T2 swizzle, setprio). Epilogue (round 6,
// verified win): per-wave padded LDS transpose buffer -> 128-B coalesced
// global writes instead of 64 scattered 2-B stores.
struct GemmSlice {
  const bf16* A; const bf16* W; const float* bias;
  bf16* dstQ; float* dstF;
  long lda; int dhalf; float scale; int mode;
};
struct GemmParams { GemmSlice s[6]; };

// per wave: 4 A-loads + 4 B-loads = 8 gll16 per tile
#define GSTAGE(kb, bA, bB) do { \
    _Pragma("unroll") \
    for (int i_ = 0; i_ < 4; ++i_) { \
      const int r0_ = w * 32 + i_ * 8; \
      gll16(Abase + (long)r0_ * lda + (kb) * 64, (bA) + r0_ * 64); \
      gll16(Wbase + (long)r0_ * 512 + (kb) * 64, (bB) + r0_ * 64); \
    } \
  } while (0)

#define GCOMPUTE(bA, bB) do { \
  _Pragma("unroll") \
  for (int ks = 0; ks < 2; ++ks) { \
    s16x8 af[4], bg[4]; \
    _Pragma("unroll") \
    for (int mi = 0; mi < 4; ++mi) { \
      const int row_ = wm + mi * 16 + fr; \
      af[mi] = *(const s16x8*)((bA) + row_ * 64 + ((ks * 32 + fq * 8) ^ ((row_ & 7) << 3))); \
    } \
    _Pragma("unroll") \
    for (int ni = 0; ni < 4; ++ni) { \
      const int row_ = wn + ni * 16 + fr; \
      bg[ni] = *(const s16x8*)((bB) + row_ * 64 + ((ks * 32 + fq * 8) ^ ((row_ & 7) << 3))); \
    } \
    __builtin_amdgcn_s_setprio(1); \
    _Pragma("unroll") \
    for (int mi = 0; mi < 4; ++mi) \
      _Pragma("unroll") \
      for (int ni = 0; ni < 4; ++ni) \
        acc[mi][ni] = __builtin_amdgcn_mfma_f32_16x16x32_bf16(af[mi], bg[ni], acc[mi][ni], 0, 0, 0); \
    __builtin_amdgcn_s_setprio(0); \
  } \
} while (0)

__global__ __launch_bounds__(256, 2) void gemm_kernel(GemmParams p) {
  __shared__ alignas(16) bf16 lds[4 * 8192];   // 64 KiB: sA0,sB0,sA1,sB1
  bf16* const sA0 = lds;
  bf16* const sB0 = lds + 8192;
  bf16* const sA1 = lds + 16384;
  bf16* const sB1 = lds + 24576;
  const GemmSlice sl = p.s[blockIdx.z];
  const long lda = sl.lda;
  const int tid = threadIdx.x;
  const int w = tid >> 6, ln = tid & 63;
  const int gm0 = blockIdx.x * 128;
  const int gn0 = blockIdx.y * 128;
  const int arow = ln >> 3;
  const int acolS = ((ln & 7) ^ (ln >> 3)) * 8;   // inverse-swizzled source column
  const int wm = (w >> 1) * 64, wn = (w & 1) * 64;
  const int fr = ln & 15, fq = ln >> 4;
  const bf16* const Abase = sl.A + (long)(gm0 + arow) * lda + acolS;
  const bf16* const Wbase = sl.W + (long)(gn0 + arow) * 512 + acolS;
  f32x4 acc[4][4] = {};

  GSTAGE(0, sA0, sB0);
  GSTAGE(1, sA1, sB1);

  for (int kt = 0; kt < 7; ++kt) {
    bf16* const bA = (kt & 1) ? sA1 : sA0;
    bf16* const bB = (kt & 1) ? sB1 : sB0;
    asm volatile("s_waitcnt vmcnt(8)" ::: "memory");   // tile kt landed; kt+1 in flight
    __builtin_amdgcn_sched_barrier(0);
    __builtin_amdgcn_s_barrier();
    GCOMPUTE(bA, bB);
    asm volatile("s_waitcnt lgkmcnt(0)" ::: "memory"); // my LDS reads complete
    __builtin_amdgcn_sched_barrier(0);
    __builtin_amdgcn_s_barrier();                      // everyone done reading buf
    if (kt < 6) GSTAGE(kt + 2, bA, bB);                // overwrite current buf
  }
  asm volatile("s_waitcnt vmcnt(0)" ::: "memory");
  __builtin_amdgcn_sched_barrier(0);
  __builtin_amdgcn_s_barrier();
  GCOMPUTE(sA1, sB1);   // tile 7

  // all waves done reading staging LDS before epilogue overwrites it
  asm volatile("s_waitcnt lgkmcnt(0)" ::: "memory");
  __builtin_amdgcn_sched_barrier(0);
  __builtin_amdgcn_s_barrier();

  // --- coalesced epilogue via per-wave LDS transpose buffer (64x72 bf16) ---
  bf16* const eW = lds + w * 4608;          // 9216 B/wave, 36,864 B total
  if (sl.mode == 0) {
    const int col0 = gn0 + wn;              // 64-aligned -> single head h
    const int h = col0 >> 6;
    const int bh = ((gm0 >> 9) << 3) + h;
    const int tb = (gm0 & 511) + wm;
#pragma unroll
    for (int ni = 0; ni < 4; ++ni) {
      const float bia = sl.bias[col0 + ni * 16 + fr];
#pragma unroll
      for (int mi = 0; mi < 4; ++mi)
#pragma unroll
        for (int r = 0; r < 4; ++r)
          eW[(mi * 16 + fq * 4 + r) * 72 + ni * 16 + fr] =
              __float2bfloat16((acc[mi][ni][r] + bia) * sl.scale);
    }
#pragma unroll
    for (int pp = 0; pp < 8; ++pp) {
      const int rr = pp * 8 + (ln >> 3);
      const s16x8 v = *(const s16x8*)(eW + rr * 72 + (ln & 7) * 8);
      *(s16x8*)(sl.dstQ + (((long)bh * 512 + tb + rr) << 7) + sl.dhalf + (ln & 7) * 8) = v;
    }
  } else if (sl.mode == 2) {
    const int col0 = gn0 + wn;
    const int h = col0 >> 6;
    const int bh = ((gm0 >> 9) << 3) + h;
    const int tb = (gm0 & 511) + wm;
    // LDS layout [dd 0..63][t 0..63 pad 72]; acc r-values are t-contiguous
#pragma unroll
    for (int ni = 0; ni < 4; ++ni) {
      const float bia = sl.bias[col0 + ni * 16 + fr];
#pragma unroll
      for (int mi = 0; mi < 4; ++mi) {
        Bf4 o;
#pragma unroll
        for (int r = 0; r < 4; ++r) o.v[r] = __float2bfloat16(acc[mi][ni][r] + bia);
        *(Bf4*)(eW + (ni * 16 + fr) * 72 + mi * 16 + fq * 4) = o;
      }
    }
#pragma unroll
    for (int pp = 0; pp < 8; ++pp) {
      const int rr = pp * 8 + (ln >> 3);   // dd index within wave tile
      const s16x8 v = *(const s16x8*)(eW + rr * 72 + (ln & 7) * 8);
      *(s16x8*)(sl.dstQ + (((long)bh * 128 + sl.dhalf + rr) << 9) + tb + (ln & 7) * 8) = v;
    }
  } else {
#pragma unroll
    for (int mi = 0; mi < 4; ++mi)
#pragma unroll
      for (int ni = 0; ni < 4; ++ni) {
        const int col = gn0 + wn + ni * 16 + fr;
        const float bia = sl.bias[col];
#pragma unroll
        for (int r = 0; r < 4; ++r) {
          const int row = gm0 + wm + mi * 16 + fq * 4 + r;
          sl.dstF[(long)row * 512 + col] = acc[mi][ni][r] + bia;
        }
      }
  }
}

// ---------------- flash attention (stage-free) ----------------
// K/V per bh = 256 KB (L3-resident; per-tile 16 KB L1-resident). Per guide
// Common-mistake #7 / m169: do NOT stage L2-fit data. Q/K/V fragments are
// read DIRECTLY from global (fragment pattern = 64 B contiguous per row,
// rows strided -> fully coalesced dwordx4). Zero barriers, zero gll16,
// zero vmcnt asm. LDS = only per-wave P buffer (16 KB) -> 4 blocks/CU.
// 4 waves/block share each K/V tile via L1. Q pre-scaled by log2e/8; no
// running max (scores bounded ~|3|). Epilogue: coalesced AO write via
// freed P buffer (8 b128 stores vs 64 scalar 2-B stores).
__global__ __launch_bounds__(256, 4) void attn_kernel(const bf16* __restrict__ Q,
                                                      const bf16* __restrict__ K,
                                                      const bf16* __restrict__ Vt,
                                                      bf16* __restrict__ AO) {
  __shared__ alignas(16) bf16 sP[8192];     // 16 KiB: 4 waves x [32][64]
  const int tid = threadIdx.x;
  const int w = tid >> 6, ln = tid & 63;
  const int fr = ln & 15, fq = ln >> 4;
  const int lg = (blockIdx.x & 7) * 128 + (blockIdx.x >> 3);
  const int bh = lg >> 2;
  const int q0 = (lg & 3) * 128;
  const long base = (long)bh << 16;         // bh * 512 * 128
  bf16* const sPw = sP + w * 2048;

  // Q fragments direct from global (read once)
  s16x8 qf[2][4];
#pragma unroll
  for (int mi = 0; mi < 2; ++mi) {
    const long qrow = base + (long)(q0 + w * 32 + mi * 16 + fr) * 128;
#pragma unroll
    for (int ks = 0; ks < 4; ++ks)
      qf[mi][ks] = *(const s16x8*)(Q + qrow + ks * 32 + fq * 8);
  }

  f32x4 o[2][8] = {};
  float lrow[2][4] = {};

  for (int kt = 0; kt < 8; ++kt) {
    // --- QK^T: K fragments direct from global ---
    f32x4 s2[2][4] = {};
#pragma unroll
    for (int ks = 0; ks < 4; ++ks) {
      s16x8 kf[4];
#pragma unroll
      for (int ni = 0; ni < 4; ++ni)
        kf[ni] = *(const s16x8*)(K + base + (long)(kt * 64 + ni * 16 + fr) * 128 + ks * 32 + fq * 8);
#pragma unroll
      for (int ni = 0; ni < 4; ++ni)
#pragma unroll
        for (int mi = 0; mi < 2; ++mi)
          s2[mi][ni] = __builtin_amdgcn_mfma_f32_16x16x32_bf16(qf[mi][ks], kf[ni], s2[mi][ni], 0, 0, 0);
    }
    // --- softmax (no running max; Q pre-scaled so exp2 direct) ---
#pragma unroll
    for (int mi = 0; mi < 2; ++mi)
#pragma unroll
      for (int r = 0; r < 4; ++r) {
        float ps = 0.f;
#pragma unroll
        for (int ni = 0; ni < 4; ++ni) {
          const float pe = __builtin_amdgcn_exp2f(s2[mi][ni][r]);
          s2[mi][ni][r] = pe; ps += pe;
        }
        ps += __shfl_xor(ps, 1); ps += __shfl_xor(ps, 2);
        ps += __shfl_xor(ps, 4); ps += __shfl_xor(ps, 8);
        lrow[mi][r] += ps;
      }
    // --- P -> per-wave LDS (swizzled), then PV with direct V loads ---
#pragma unroll
    for (int mi = 0; mi < 2; ++mi)
#pragma unroll
      for (int ni = 0; ni < 4; ++ni)
#pragma unroll
        for (int r = 0; r < 4; ++r) {
          const int rp = mi * 16 + fq * 4 + r;
          sPw[rp * 64 + ((ni * 16 + fr) ^ ((rp & 7) << 3))] = __float2bfloat16(s2[mi][ni][r]);
        }
#pragma unroll
    for (int ks2 = 0; ks2 < 2; ++ks2) {
      s16x8 pf[2];
#pragma unroll
      for (int mi = 0; mi < 2; ++mi) {
        const int row_ = mi * 16 + fr;
        pf[mi] = *(const s16x8*)(sPw + row_ * 64 + ((ks2 * 32 + fq * 8) ^ ((row_ & 7) << 3)));
      }
#pragma unroll
      for (int nj = 0; nj < 8; ++nj) {
        const s16x8 vf = *(const s16x8*)(Vt + base + (long)(nj * 16 + fr) * 512 + kt * 64 + ks2 * 32 + fq * 8);
#pragma unroll
        for (int mi = 0; mi < 2; ++mi)
          o[mi][nj] = __builtin_amdgcn_mfma_f32_16x16x32_bf16(pf[mi], vf, o[mi][nj], 0, 0, 0);
      }
    }
  }

  // --- epilogue: O /= l; coalesced AO writes via freed sPw ---
  const int b = bh >> 3, h = bh & 7;
  float rl[2][4];
#pragma unroll
  for (int mi = 0; mi < 2; ++mi)
#pragma unroll
    for (int r = 0; r < 4; ++r) rl[mi][r] = 1.f / lrow[mi][r];
#pragma unroll
  for (int hh = 0; hh < 2; ++hh) {
#pragma unroll
    for (int mi = 0; mi < 2; ++mi)
#pragma unroll
      for (int nj4 = 0; nj4 < 4; ++nj4)
#pragma unroll
        for (int r = 0; r < 4; ++r) {
          const int rp = mi * 16 + fq * 4 + r;
          sPw[rp * 64 + ((nj4 * 16 + fr) ^ ((rp & 7) << 3))] =
              __float2bfloat16(o[mi][hh * 4 + nj4][r] * rl[mi][r]);
        }
#pragma unroll
    for (int pp = 0; pp < 4; ++pp) {
      const int rr = pp * 8 + (ln >> 3);
      const s16x8 v = *(const s16x8*)(sPw + rr * 64 + (((ln & 7) * 8) ^ ((rr & 7) << 3)));
      *(s16x8*)(AO + (((long)(b * 512 + q0 + w * 32 + rr)) << 10) + h * 128 + hh * 64 + (ln & 7) * 8) = v;
    }
  }
}

// ---------------- launch ----------------
extern "C" void kernel_launch(void* const* d_in, const int* in_sizes, int n_in,
                              void* d_out, int out_size, void* d_ws, size_t ws_size,
                              hipStream_t stream) {
  const float* xf = (const float*)d_in[0];
  const float* xs = (const float*)d_in[1];
  // weight order in WW: 0=wq1,1=wk1,2=wv1,3=wq2,4=wk2,5=wv2,6=wo1,7=wo2
  const float* w_f[8] = { (const float*)d_in[2], (const float*)d_in[4], (const float*)d_in[6],
                          (const float*)d_in[8], (const float*)d_in[10], (const float*)d_in[12],
                          (const float*)d_in[14], (const float*)d_in[16] };

  bf16* ws = (bf16*)d_ws;
  bf16* XF = ws;                       // 8,388,608 bf16
  bf16* XS = ws + 8388608;             // 8,388,608
  bf16* WW = ws + 16777216;            // 8 x 262,144
  bf16* Qb = ws + 18874368;            // 16,777,216 each
  bf16* Kb = Qb + 16777216;
  bf16* Vb = Kb + 16777216;            // V^T layout (bh, d, t)
  bf16* AO = ws;                       // reuse XF+XS region

  ConvParams cp;
  cp.j[0] = { xf, XF, 2097152, 0 };
  cp.j[1] = { xs, XS, 2097152, 0 };
  for (int i = 0; i < 8; ++i) cp.j[2 + i] = { w_f[i], WW + i * 262144, 65536, 0 };
  convert_kernel<<<dim3(512, 1, 10), 256, 0, stream>>>(cp);

  const float qsc = 0.125f * 1.44269504088896f;   // fold log2(e) so attn uses exp2
  GemmParams gp;
  gp.s[0] = { XF, WW + 0 * 262144, (const float*)d_in[3],  Qb, nullptr, 512, 0,  qsc, 0 };
  gp.s[1] = { XS, WW + 3 * 262144, (const float*)d_in[9],  Qb, nullptr, 512, 64, qsc, 0 };
  gp.s[2] = { XF, WW + 1 * 262144, (const float*)d_in[5],  Kb, nullptr, 512, 0,  1.f, 0 };
  gp.s[3] = { XS, WW + 4 * 262144, (const float*)d_in[11], Kb, nullptr, 512, 64, 1.f, 0 };
  gp.s[4] = { XF, WW + 2 * 262144, (const float*)d_in[7],  Vb, nullptr, 512, 0,  1.f, 2 };
  gp.s[5] = { XS, WW + 5 * 262144, (const float*)d_in[13], Vb, nullptr, 512, 64, 1.f, 2 };
  gemm_kernel<<<dim3(128, 4, 6), 256, 0, stream>>>(gp);

  attn_kernel<<<dim3(1024), 256, 0, stream>>>(Qb, Kb, Vb, AO);

  float* out = (float*)d_out;
  GemmParams op;
  op.s[0] = { AO,       WW + 6 * 262144, (const float*)d_in[15], nullptr, out,           1024, 0, 1.f, 1 };
  op.s[1] = { AO + 512, WW + 7 * 262144, (const float*)d_in[17], nullptr, out + 8388608, 1024, 0, 1.f, 1 };
  op.s[2] = op.s[0]; op.s[3] = op.s[0]; op.s[4] = op.s[0]; op.s[5] = op.s[0];
  gemm_kernel<<<dim3(128, 4, 2), 256, 0, stream>>>(op);
}

// Round 8
// 231.787 us; speedup vs baseline: 1.4774x; 1.4774x over previous
//
#include <hip/hip_runtime.h>
#include <hip/hip_bf16.h>
#include <stdint.h>

typedef __hip_bfloat16 bf16;
using f32x4 = __attribute__((ext_vector_type(4))) float;
using s16x8 = __attribute__((ext_vector_type(8))) short;

typedef __attribute__((address_space(1))) unsigned int gu32;
typedef __attribute__((address_space(3))) unsigned int lu32;

__device__ __forceinline__ void gll16(const void* g, void* l) {
  __builtin_amdgcn_global_load_lds((const gu32*)g, (lu32*)l, 16, 0, 0);
}

// ---------------- convert f32 -> bf16 ----------------
struct ConvJob { const float* src; bf16* dst; int n4; int pad; };
struct ConvParams { ConvJob j[10]; };
struct alignas(8) Bf4 { bf16 v[4]; };

__global__ void convert_kernel(ConvParams p) {
  ConvJob jb = p.j[blockIdx.z];
  int stride = gridDim.x * blockDim.x;
  for (int i = blockIdx.x * blockDim.x + threadIdx.x; i < jb.n4; i += stride) {
    float4 v = ((const float4*)jb.src)[i];
    Bf4 o;
    o.v[0] = __float2bfloat16(v.x);
    o.v[1] = __float2bfloat16(v.y);
    o.v[2] = __float2bfloat16(v.z);
    o.v[3] = __float2bfloat16(v.w);
    ((Bf4*)jb.dst)[i] = o;
  }
}

// ---------------- GEMM: C = A(MxK) @ W(NxK)^T + bias ----------------
// K-loop: round-1 verified structure (128x128 tile, 256 thr, 4 waves 2x2,
// dbuf 64 KiB, counted vmcnt(8), T2 swizzle, setprio). Epilogue (round 6,
// verified win): per-wave padded LDS transpose buffer -> 128-B coalesced
// global writes instead of 64 scattered 2-B stores.
struct GemmSlice {
  const bf16* A; const bf16* W; const float* bias;
  bf16* dstQ; float* dstF;
  long lda; int dhalf; float scale; int mode;
};
struct GemmParams { GemmSlice s[6]; };

// per wave: 4 A-loads + 4 B-loads = 8 gll16 per tile
#define GSTAGE(kb, bA, bB) do { \
    _Pragma("unroll") \
    for (int i_ = 0; i_ < 4; ++i_) { \
      const int r0_ = w * 32 + i_ * 8; \
      gll16(Abase + (long)r0_ * lda + (kb) * 64, (bA) + r0_ * 64); \
      gll16(Wbase + (long)r0_ * 512 + (kb) * 64, (bB) + r0_ * 64); \
    } \
  } while (0)

#define GCOMPUTE(bA, bB) do { \
  _Pragma("unroll") \
  for (int ks = 0; ks < 2; ++ks) { \
    s16x8 af[4], bg[4]; \
    _Pragma("unroll") \
    for (int mi = 0; mi < 4; ++mi) { \
      const int row_ = wm + mi * 16 + fr; \
      af[mi] = *(const s16x8*)((bA) + row_ * 64 + ((ks * 32 + fq * 8) ^ ((row_ & 7) << 3))); \
    } \
    _Pragma("unroll") \
    for (int ni = 0; ni < 4; ++ni) { \
      const int row_ = wn + ni * 16 + fr; \
      bg[ni] = *(const s16x8*)((bB) + row_ * 64 + ((ks * 32 + fq * 8) ^ ((row_ & 7) << 3))); \
    } \
    __builtin_amdgcn_s_setprio(1); \
    _Pragma("unroll") \
    for (int mi = 0; mi < 4; ++mi) \
      _Pragma("unroll") \
      for (int ni = 0; ni < 4; ++ni) \
        acc[mi][ni] = __builtin_amdgcn_mfma_f32_16x16x32_bf16(af[mi], bg[ni], acc[mi][ni], 0, 0, 0); \
    __builtin_amdgcn_s_setprio(0); \
  } \
} while (0)

__global__ __launch_bounds__(256, 2) void gemm_kernel(GemmParams p) {
  __shared__ alignas(16) bf16 lds[4 * 8192];   // 64 KiB: sA0,sB0,sA1,sB1
  bf16* const sA0 = lds;
  bf16* const sB0 = lds + 8192;
  bf16* const sA1 = lds + 16384;
  bf16* const sB1 = lds + 24576;
  const GemmSlice sl = p.s[blockIdx.z];
  const long lda = sl.lda;
  const int tid = threadIdx.x;
  const int w = tid >> 6, ln = tid & 63;
  const int gm0 = blockIdx.x * 128;
  const int gn0 = blockIdx.y * 128;
  const int arow = ln >> 3;
  const int acolS = ((ln & 7) ^ (ln >> 3)) * 8;   // inverse-swizzled source column
  const int wm = (w >> 1) * 64, wn = (w & 1) * 64;
  const int fr = ln & 15, fq = ln >> 4;
  const bf16* const Abase = sl.A + (long)(gm0 + arow) * lda + acolS;
  const bf16* const Wbase = sl.W + (long)(gn0 + arow) * 512 + acolS;
  f32x4 acc[4][4] = {};

  GSTAGE(0, sA0, sB0);
  GSTAGE(1, sA1, sB1);

  for (int kt = 0; kt < 7; ++kt) {
    bf16* const bA = (kt & 1) ? sA1 : sA0;
    bf16* const bB = (kt & 1) ? sB1 : sB0;
    asm volatile("s_waitcnt vmcnt(8)" ::: "memory");   // tile kt landed; kt+1 in flight
    __builtin_amdgcn_sched_barrier(0);
    __builtin_amdgcn_s_barrier();
    GCOMPUTE(bA, bB);
    asm volatile("s_waitcnt lgkmcnt(0)" ::: "memory"); // my LDS reads complete
    __builtin_amdgcn_sched_barrier(0);
    __builtin_amdgcn_s_barrier();                      // everyone done reading buf
    if (kt < 6) GSTAGE(kt + 2, bA, bB);                // overwrite current buf
  }
  asm volatile("s_waitcnt vmcnt(0)" ::: "memory");
  __builtin_amdgcn_sched_barrier(0);
  __builtin_amdgcn_s_barrier();
  GCOMPUTE(sA1, sB1);   // tile 7

  // all waves done reading staging LDS before epilogue overwrites it
  asm volatile("s_waitcnt lgkmcnt(0)" ::: "memory");
  __builtin_amdgcn_sched_barrier(0);
  __builtin_amdgcn_s_barrier();

  // --- coalesced epilogue via per-wave LDS transpose buffer (64x72 bf16) ---
  bf16* const eW = lds + w * 4608;          // 9216 B/wave, 36,864 B total
  if (sl.mode == 0) {
    const int col0 = gn0 + wn;              // 64-aligned -> single head h
    const int h = col0 >> 6;
    const int bh = ((gm0 >> 9) << 3) + h;
    const int tb = (gm0 & 511) + wm;
#pragma unroll
    for (int ni = 0; ni < 4; ++ni) {
      const float bia = sl.bias[col0 + ni * 16 + fr];
#pragma unroll
      for (int mi = 0; mi < 4; ++mi)
#pragma unroll
        for (int r = 0; r < 4; ++r)
          eW[(mi * 16 + fq * 4 + r) * 72 + ni * 16 + fr] =
              __float2bfloat16((acc[mi][ni][r] + bia) * sl.scale);
    }
#pragma unroll
    for (int pp = 0; pp < 8; ++pp) {
      const int rr = pp * 8 + (ln >> 3);
      const s16x8 v = *(const s16x8*)(eW + rr * 72 + (ln & 7) * 8);
      *(s16x8*)(sl.dstQ + (((long)bh * 512 + tb + rr) << 7) + sl.dhalf + (ln & 7) * 8) = v;
    }
  } else if (sl.mode == 2) {
    const int col0 = gn0 + wn;
    const int h = col0 >> 6;
    const int bh = ((gm0 >> 9) << 3) + h;
    const int tb = (gm0 & 511) + wm;
    // LDS layout [dd 0..63][t 0..63 pad 72]; acc r-values are t-contiguous
#pragma unroll
    for (int ni = 0; ni < 4; ++ni) {
      const float bia = sl.bias[col0 + ni * 16 + fr];
#pragma unroll
      for (int mi = 0; mi < 4; ++mi) {
        Bf4 o;
#pragma unroll
        for (int r = 0; r < 4; ++r) o.v[r] = __float2bfloat16(acc[mi][ni][r] + bia);
        *(Bf4*)(eW + (ni * 16 + fr) * 72 + mi * 16 + fq * 4) = o;
      }
    }
#pragma unroll
    for (int pp = 0; pp < 8; ++pp) {
      const int rr = pp * 8 + (ln >> 3);   // dd index within wave tile
      const s16x8 v = *(const s16x8*)(eW + rr * 72 + (ln & 7) * 8);
      *(s16x8*)(sl.dstQ + (((long)bh * 128 + sl.dhalf + rr) << 9) + tb + (ln & 7) * 8) = v;
    }
  } else {
#pragma unroll
    for (int mi = 0; mi < 4; ++mi)
#pragma unroll
      for (int ni = 0; ni < 4; ++ni) {
        const int col = gn0 + wn + ni * 16 + fr;
        const float bia = sl.bias[col];
#pragma unroll
        for (int r = 0; r < 4; ++r) {
          const int row = gm0 + wm + mi * 16 + fq * 4 + r;
          sl.dstF[(long)row * 512 + col] = acc[mi][ni][r] + bia;
        }
      }
  }
}

// ---------------- flash attention (stage-free, reg-budget fixed) ----------------
// Round-7 concept, round-8 fix: __launch_bounds__(256, 2) so the compiler
// gets a 256-VGPR budget (round 7's (256,4) capped at 64 -> full acc spill,
// FETCH 446 MB, 254 us — measured scratch BW, not the design).
// K/V per bh = 256 KB (L3-resident; per-tile-pair 32 KB = L1-resident,
// shared by the block's 4 waves). Q/K/V fragments read DIRECTLY from global
// (64-B contiguous per row -> coalesced dwordx4). Zero barriers, zero
// gll16, zero vmcnt. LDS = 16 KiB (per-wave P buffer) -> 3 blocks/CU at
// ~170 VGPR. Q pre-scaled by log2e/8; no running max (scores bounded ~|3|).
// Epilogue: coalesced AO write via freed P buffer.
__global__ __launch_bounds__(256, 2) void attn_kernel(const bf16* __restrict__ Q,
                                                      const bf16* __restrict__ K,
                                                      const bf16* __restrict__ Vt,
                                                      bf16* __restrict__ AO) {
  __shared__ alignas(16) bf16 sP[8192];     // 16 KiB: 4 waves x [32][64]
  const int tid = threadIdx.x;
  const int w = tid >> 6, ln = tid & 63;
  const int fr = ln & 15, fq = ln >> 4;
  const int lg = (blockIdx.x & 7) * 128 + (blockIdx.x >> 3);
  const int bh = lg >> 2;
  const int q0 = (lg & 3) * 128;
  const long base = (long)bh << 16;         // bh * 512 * 128
  bf16* const sPw = sP + w * 2048;

  // Q fragments direct from global (read once)
  s16x8 qf[2][4];
#pragma unroll
  for (int mi = 0; mi < 2; ++mi) {
    const long qrow = base + (long)(q0 + w * 32 + mi * 16 + fr) * 128;
#pragma unroll
    for (int ks = 0; ks < 4; ++ks)
      qf[mi][ks] = *(const s16x8*)(Q + qrow + ks * 32 + fq * 8);
  }

  f32x4 o[2][8] = {};
  float lrow[2][4] = {};

  for (int kt = 0; kt < 8; ++kt) {
    // --- QK^T: K fragments direct from global ---
    f32x4 s2[2][4] = {};
#pragma unroll
    for (int ks = 0; ks < 4; ++ks) {
      s16x8 kf[4];
#pragma unroll
      for (int ni = 0; ni < 4; ++ni)
        kf[ni] = *(const s16x8*)(K + base + (long)(kt * 64 + ni * 16 + fr) * 128 + ks * 32 + fq * 8);
#pragma unroll
      for (int ni = 0; ni < 4; ++ni)
#pragma unroll
        for (int mi = 0; mi < 2; ++mi)
          s2[mi][ni] = __builtin_amdgcn_mfma_f32_16x16x32_bf16(qf[mi][ks], kf[ni], s2[mi][ni], 0, 0, 0);
    }
    // --- softmax (no running max; Q pre-scaled so exp2 direct) ---
#pragma unroll
    for (int mi = 0; mi < 2; ++mi)
#pragma unroll
      for (int r = 0; r < 4; ++r) {
        float ps = 0.f;
#pragma unroll
        for (int ni = 0; ni < 4; ++ni) {
          const float pe = __builtin_amdgcn_exp2f(s2[mi][ni][r]);
          s2[mi][ni][r] = pe; ps += pe;
        }
        ps += __shfl_xor(ps, 1); ps += __shfl_xor(ps, 2);
        ps += __shfl_xor(ps, 4); ps += __shfl_xor(ps, 8);
        lrow[mi][r] += ps;
      }
    // --- P -> per-wave LDS (swizzled), then PV with direct V loads ---
#pragma unroll
    for (int mi = 0; mi < 2; ++mi)
#pragma unroll
      for (int ni = 0; ni < 4; ++ni)
#pragma unroll
        for (int r = 0; r < 4; ++r) {
          const int rp = mi * 16 + fq * 4 + r;
          sPw[rp * 64 + ((ni * 16 + fr) ^ ((rp & 7) << 3))] = __float2bfloat16(s2[mi][ni][r]);
        }
#pragma unroll
    for (int ks2 = 0; ks2 < 2; ++ks2) {
      s16x8 pf[2];
#pragma unroll
      for (int mi = 0; mi < 2; ++mi) {
        const int row_ = mi * 16 + fr;
        pf[mi] = *(const s16x8*)(sPw + row_ * 64 + ((ks2 * 32 + fq * 8) ^ ((row_ & 7) << 3)));
      }
#pragma unroll
      for (int nj = 0; nj < 8; ++nj) {
        const s16x8 vf = *(const s16x8*)(Vt + base + (long)(nj * 16 + fr) * 512 + kt * 64 + ks2 * 32 + fq * 8);
#pragma unroll
        for (int mi = 0; mi < 2; ++mi)
          o[mi][nj] = __builtin_amdgcn_mfma_f32_16x16x32_bf16(pf[mi], vf, o[mi][nj], 0, 0, 0);
      }
    }
  }

  // --- epilogue: O /= l; coalesced AO writes via freed sPw ---
  const int b = bh >> 3, h = bh & 7;
  float rl[2][4];
#pragma unroll
  for (int mi = 0; mi < 2; ++mi)
#pragma unroll
    for (int r = 0; r < 4; ++r) rl[mi][r] = 1.f / lrow[mi][r];
#pragma unroll
  for (int hh = 0; hh < 2; ++hh) {
#pragma unroll
    for (int mi = 0; mi < 2; ++mi)
#pragma unroll
      for (int nj4 = 0; nj4 < 4; ++nj4)
#pragma unroll
        for (int r = 0; r < 4; ++r) {
          const int rp = mi * 16 + fq * 4 + r;
          sPw[rp * 64 + ((nj4 * 16 + fr) ^ ((rp & 7) << 3))] =
              __float2bfloat16(o[mi][hh * 4 + nj4][r] * rl[mi][r]);
        }
#pragma unroll
    for (int pp = 0; pp < 4; ++pp) {
      const int rr = pp * 8 + (ln >> 3);
      const s16x8 v = *(const s16x8*)(sPw + rr * 64 + (((ln & 7) * 8) ^ ((rr & 7) << 3)));
      *(s16x8*)(AO + (((long)(b * 512 + q0 + w * 32 + rr)) << 10) + h * 128 + hh * 64 + (ln & 7) * 8) = v;
    }
  }
}

// ---------------- launch ----------------
extern "C" void kernel_launch(void* const* d_in, const int* in_sizes, int n_in,
                              void* d_out, int out_size, void* d_ws, size_t ws_size,
                              hipStream_t stream) {
  const float* xf = (const float*)d_in[0];
  const float* xs = (const float*)d_in[1];
  // weight order in WW: 0=wq1,1=wk1,2=wv1,3=wq2,4=wk2,5=wv2,6=wo1,7=wo2
  const float* w_f[8] = { (const float*)d_in[2], (const float*)d_in[4], (const float*)d_in[6],
                          (const float*)d_in[8], (const float*)d_in[10], (const float*)d_in[12],
                          (const float*)d_in[14], (const float*)d_in[16] };

  bf16* ws = (bf16*)d_ws;
  bf16* XF = ws;                       // 8,388,608 bf16
  bf16* XS = ws + 8388608;             // 8,388,608
  bf16* WW = ws + 16777216;            // 8 x 262,144
  bf16* Qb = ws + 18874368;            // 16,777,216 each
  bf16* Kb = Qb + 16777216;
  bf16* Vb = Kb + 16777216;            // V^T layout (bh, d, t)
  bf16* AO = ws;                       // reuse XF+XS region

  ConvParams cp;
  cp.j[0] = { xf, XF, 2097152, 0 };
  cp.j[1] = { xs, XS, 2097152, 0 };
  for (int i = 0; i < 8; ++i) cp.j[2 + i] = { w_f[i], WW + i * 262144, 65536, 0 };
  convert_kernel<<<dim3(512, 1, 10), 256, 0, stream>>>(cp);

  const float qsc = 0.125f * 1.44269504088896f;   // fold log2(e) so attn uses exp2
  GemmParams gp;
  gp.s[0] = { XF, WW + 0 * 262144, (const float*)d_in[3],  Qb, nullptr, 512, 0,  qsc, 0 };
  gp.s[1] = { XS, WW + 3 * 262144, (const float*)d_in[9],  Qb, nullptr, 512, 64, qsc, 0 };
  gp.s[2] = { XF, WW + 1 * 262144, (const float*)d_in[5],  Kb, nullptr, 512, 0,  1.f, 0 };
  gp.s[3] = { XS, WW + 4 * 262144, (const float*)d_in[11], Kb, nullptr, 512, 64, 1.f, 0 };
  gp.s[4] = { XF, WW + 2 * 262144, (const float*)d_in[7],  Vb, nullptr, 512, 0,  1.f, 2 };
  gp.s[5] = { XS, WW + 5 * 262144, (const float*)d_in[13], Vb, nullptr, 512, 64, 1.f, 2 };
  gemm_kernel<<<dim3(128, 4, 6), 256, 0, stream>>>(gp);

  attn_kernel<<<dim3(1024), 256, 0, stream>>>(Qb, Kb, Vb, AO);

  float* out = (float*)d_out;
  GemmParams op;
  op.s[0] = { AO,       WW + 6 * 262144, (const float*)d_in[15], nullptr, out,           1024, 0, 1.f, 1 };
  op.s[1] = { AO + 512, WW + 7 * 262144, (const float*)d_in[17], nullptr, out + 8388608, 1024, 0, 1.f, 1 };
  op.s[2] = op.s[0]; op.s[3] = op.s[0]; op.s[4] = op.s[0]; op.s[5] = op.s[0];
  gemm_kernel<<<dim3(128, 4, 2), 256, 0, stream>>>(op);
}

// Round 9
// 170.530 us; speedup vs baseline: 2.0082x; 1.3592x over previous
//
#include <hip/hip_runtime.h>
#include <hip/hip_bf16.h>
#include <stdint.h>

typedef __hip_bfloat16 bf16;
using f32x4 = __attribute__((ext_vector_type(4))) float;
using s16x8 = __attribute__((ext_vector_type(8))) short;

typedef __attribute__((address_space(1))) unsigned int gu32;
typedef __attribute__((address_space(3))) unsigned int lu32;

__device__ __forceinline__ void gll16(const void* g, void* l) {
  __builtin_amdgcn_global_load_lds((const gu32*)g, (lu32*)l, 16, 0, 0);
}

// ---------------- convert f32 -> bf16 ----------------
struct ConvJob { const float* src; bf16* dst; int n4; int pad; };
struct ConvParams { ConvJob j[10]; };
struct alignas(8) Bf4 { bf16 v[4]; };

__global__ void convert_kernel(ConvParams p) {
  ConvJob jb = p.j[blockIdx.z];
  int stride = gridDim.x * blockDim.x;
  for (int i = blockIdx.x * blockDim.x + threadIdx.x; i < jb.n4; i += stride) {
    float4 v = ((const float4*)jb.src)[i];
    Bf4 o;
    o.v[0] = __float2bfloat16(v.x);
    o.v[1] = __float2bfloat16(v.y);
    o.v[2] = __float2bfloat16(v.z);
    o.v[3] = __float2bfloat16(v.w);
    ((Bf4*)jb.dst)[i] = o;
  }
}

// ---------------- GEMM: C = A(MxK) @ W(NxK)^T + bias ----------------
// K-loop: round-1 verified structure (128x128 tile, 256 thr, 4 waves 2x2,
// dbuf 64 KiB, counted vmcnt(8), T2 swizzle, setprio). Epilogue (round 6,
// verified win): per-wave padded LDS transpose buffer -> 128-B coalesced
// global writes instead of 64 scattered 2-B stores.
struct GemmSlice {
  const bf16* A; const bf16* W; const float* bias;
  bf16* dstQ; float* dstF;
  long lda; int dhalf; float scale; int mode;
};
struct GemmParams { GemmSlice s[6]; };

// per wave: 4 A-loads + 4 B-loads = 8 gll16 per tile
#define GSTAGE(kb, bA, bB) do { \
    _Pragma("unroll") \
    for (int i_ = 0; i_ < 4; ++i_) { \
      const int r0_ = w * 32 + i_ * 8; \
      gll16(Abase + (long)r0_ * lda + (kb) * 64, (bA) + r0_ * 64); \
      gll16(Wbase + (long)r0_ * 512 + (kb) * 64, (bB) + r0_ * 64); \
    } \
  } while (0)

#define GCOMPUTE(bA, bB) do { \
  _Pragma("unroll") \
  for (int ks = 0; ks < 2; ++ks) { \
    s16x8 af[4], bg[4]; \
    _Pragma("unroll") \
    for (int mi = 0; mi < 4; ++mi) { \
      const int row_ = wm + mi * 16 + fr; \
      af[mi] = *(const s16x8*)((bA) + row_ * 64 + ((ks * 32 + fq * 8) ^ ((row_ & 7) << 3))); \
    } \
    _Pragma("unroll") \
    for (int ni = 0; ni < 4; ++ni) { \
      const int row_ = wn + ni * 16 + fr; \
      bg[ni] = *(const s16x8*)((bB) + row_ * 64 + ((ks * 32 + fq * 8) ^ ((row_ & 7) << 3))); \
    } \
    __builtin_amdgcn_s_setprio(1); \
    _Pragma("unroll") \
    for (int mi = 0; mi < 4; ++mi) \
      _Pragma("unroll") \
      for (int ni = 0; ni < 4; ++ni) \
        acc[mi][ni] = __builtin_amdgcn_mfma_f32_16x16x32_bf16(af[mi], bg[ni], acc[mi][ni], 0, 0, 0); \
    __builtin_amdgcn_s_setprio(0); \
  } \
} while (0)

__global__ __launch_bounds__(256, 2) void gemm_kernel(GemmParams p) {
  __shared__ alignas(16) bf16 lds[4 * 8192];   // 64 KiB: sA0,sB0,sA1,sB1
  bf16* const sA0 = lds;
  bf16* const sB0 = lds + 8192;
  bf16* const sA1 = lds + 16384;
  bf16* const sB1 = lds + 24576;
  const GemmSlice sl = p.s[blockIdx.z];
  const long lda = sl.lda;
  const int tid = threadIdx.x;
  const int w = tid >> 6, ln = tid & 63;
  const int gm0 = blockIdx.x * 128;
  const int gn0 = blockIdx.y * 128;
  const int arow = ln >> 3;
  const int acolS = ((ln & 7) ^ (ln >> 3)) * 8;   // inverse-swizzled source column
  const int wm = (w >> 1) * 64, wn = (w & 1) * 64;
  const int fr = ln & 15, fq = ln >> 4;
  const bf16* const Abase = sl.A + (long)(gm0 + arow) * lda + acolS;
  const bf16* const Wbase = sl.W + (long)(gn0 + arow) * 512 + acolS;
  f32x4 acc[4][4] = {};

  GSTAGE(0, sA0, sB0);
  GSTAGE(1, sA1, sB1);

  for (int kt = 0; kt < 7; ++kt) {
    bf16* const bA = (kt & 1) ? sA1 : sA0;
    bf16* const bB = (kt & 1) ? sB1 : sB0;
    asm volatile("s_waitcnt vmcnt(8)" ::: "memory");   // tile kt landed; kt+1 in flight
    __builtin_amdgcn_sched_barrier(0);
    __builtin_amdgcn_s_barrier();
    GCOMPUTE(bA, bB);
    asm volatile("s_waitcnt lgkmcnt(0)" ::: "memory"); // my LDS reads complete
    __builtin_amdgcn_sched_barrier(0);
    __builtin_amdgcn_s_barrier();                      // everyone done reading buf
    if (kt < 6) GSTAGE(kt + 2, bA, bB);                // overwrite current buf
  }
  asm volatile("s_waitcnt vmcnt(0)" ::: "memory");
  __builtin_amdgcn_sched_barrier(0);
  __builtin_amdgcn_s_barrier();
  GCOMPUTE(sA1, sB1);   // tile 7

  // all waves done reading staging LDS before epilogue overwrites it
  asm volatile("s_waitcnt lgkmcnt(0)" ::: "memory");
  __builtin_amdgcn_sched_barrier(0);
  __builtin_amdgcn_s_barrier();

  // --- coalesced epilogue via per-wave LDS transpose buffer (64x72 bf16) ---
  bf16* const eW = lds + w * 4608;          // 9216 B/wave, 36,864 B total
  if (sl.mode == 0) {
    const int col0 = gn0 + wn;              // 64-aligned -> single head h
    const int h = col0 >> 6;
    const int bh = ((gm0 >> 9) << 3) + h;
    const int tb = (gm0 & 511) + wm;
#pragma unroll
    for (int ni = 0; ni < 4; ++ni) {
      const float bia = sl.bias[col0 + ni * 16 + fr];
#pragma unroll
      for (int mi = 0; mi < 4; ++mi)
#pragma unroll
        for (int r = 0; r < 4; ++r)
          eW[(mi * 16 + fq * 4 + r) * 72 + ni * 16 + fr] =
              __float2bfloat16((acc[mi][ni][r] + bia) * sl.scale);
    }
#pragma unroll
    for (int pp = 0; pp < 8; ++pp) {
      const int rr = pp * 8 + (ln >> 3);
      const s16x8 v = *(const s16x8*)(eW + rr * 72 + (ln & 7) * 8);
      *(s16x8*)(sl.dstQ + (((long)bh * 512 + tb + rr) << 7) + sl.dhalf + (ln & 7) * 8) = v;
    }
  } else if (sl.mode == 2) {
    const int col0 = gn0 + wn;
    const int h = col0 >> 6;
    const int bh = ((gm0 >> 9) << 3) + h;
    const int tb = (gm0 & 511) + wm;
    // LDS layout [dd 0..63][t 0..63 pad 72]; acc r-values are t-contiguous
#pragma unroll
    for (int ni = 0; ni < 4; ++ni) {
      const float bia = sl.bias[col0 + ni * 16 + fr];
#pragma unroll
      for (int mi = 0; mi < 4; ++mi) {
        Bf4 o;
#pragma unroll
        for (int r = 0; r < 4; ++r) o.v[r] = __float2bfloat16(acc[mi][ni][r] + bia);
        *(Bf4*)(eW + (ni * 16 + fr) * 72 + mi * 16 + fq * 4) = o;
      }
    }
#pragma unroll
    for (int pp = 0; pp < 8; ++pp) {
      const int rr = pp * 8 + (ln >> 3);   // dd index within wave tile
      const s16x8 v = *(const s16x8*)(eW + rr * 72 + (ln & 7) * 8);
      *(s16x8*)(sl.dstQ + (((long)bh * 128 + sl.dhalf + rr) << 9) + tb + (ln & 7) * 8) = v;
    }
  } else {
#pragma unroll
    for (int mi = 0; mi < 4; ++mi)
#pragma unroll
      for (int ni = 0; ni < 4; ++ni) {
        const int col = gn0 + wn + ni * 16 + fr;
        const float bia = sl.bias[col];
#pragma unroll
        for (int r = 0; r < 4; ++r) {
          const int row = gm0 + wm + mi * 16 + fq * 4 + r;
          sl.dstF[(long)row * 512 + col] = acc[mi][ni][r] + bia;
        }
      }
  }
}

// ---------------- flash attention (8-wave, staged; round-6 structure widened) ----------------
// Round-6 verified staged structure, widened: 512 threads = 8 waves x 32
// q-rows = 256 q-rows/block -> 2 blocks per bh (grid 512), halving total
// K/V staging (262 -> 131 MB) and per-wave staging issue (4 gll16/tile).
// Inner COMPUTE, dbuf, counted vmcnt, swizzle identical to round 6.
// LDS 96 KiB (KV dbuf 64 + sP 32) -> 1 block/CU, 8 waves (2/SIMD).
// Q pre-scaled by log2e/8; no running max (scores bounded ~|3|).
#define STAGE(kt, bK, bV) do { \
    gll16(kgb + (kt) * 8192, (bK) + tid * 8); \
    gll16(kgb + (kt) * 8192 + 4096, (bK) + tid * 8 + 4096); \
    gll16(vgb + (kt) * 64, (bV) + tid * 8); \
    gll16(vgb + (kt) * 64 + 32768, (bV) + tid * 8 + 4096); \
  } while (0)

#define COMPUTE(bK, bV) do { \
  f32x4 s2[2][4] = {}; \
  _Pragma("unroll") \
  for (int ks = 0; ks < 4; ++ks) { \
    _Pragma("unroll") \
    for (int ni = 0; ni < 4; ++ni) { \
      const int row_ = ni * 16 + fr; \
      const s16x8 kf = *(const s16x8*)((bK) + row_ * 128 + ((ks * 32 + fq * 8) ^ ((row_ & 7) << 3))); \
      _Pragma("unroll") \
      for (int mi = 0; mi < 2; ++mi) \
        s2[mi][ni] = __builtin_amdgcn_mfma_f32_16x16x32_bf16(qf[mi][ks], kf, s2[mi][ni], 0, 0, 0); \
    } \
  } \
  _Pragma("unroll") \
  for (int mi = 0; mi < 2; ++mi) \
    _Pragma("unroll") \
    for (int r = 0; r < 4; ++r) { \
      float ps = 0.f; \
      _Pragma("unroll") \
      for (int ni = 0; ni < 4; ++ni) { \
        const float pe = __builtin_amdgcn_exp2f(s2[mi][ni][r]); \
        s2[mi][ni][r] = pe; ps += pe; \
      } \
      ps += __shfl_xor(ps, 1); ps += __shfl_xor(ps, 2); \
      ps += __shfl_xor(ps, 4); ps += __shfl_xor(ps, 8); \
      lrow[mi][r] += ps; \
    } \
  _Pragma("unroll") \
  for (int mi = 0; mi < 2; ++mi) \
    _Pragma("unroll") \
    for (int ni = 0; ni < 4; ++ni) \
      _Pragma("unroll") \
      for (int r = 0; r < 4; ++r) { \
        const int rp = mi * 16 + fq * 4 + r; \
        sPw[rp * 64 + ((ni * 16 + fr) ^ ((rp & 7) << 3))] = __float2bfloat16(s2[mi][ni][r]); \
      } \
  _Pragma("unroll") \
  for (int ks = 0; ks < 2; ++ks) { \
    s16x8 pf[2]; \
    _Pragma("unroll") \
    for (int mi = 0; mi < 2; ++mi) { \
      const int row_ = mi * 16 + fr; \
      pf[mi] = *(const s16x8*)(sPw + row_ * 64 + ((ks * 32 + fq * 8) ^ ((row_ & 7) << 3))); \
    } \
    _Pragma("unroll") \
    for (int nj = 0; nj < 8; ++nj) { \
      const int row_ = nj * 16 + fr; \
      const s16x8 vf = *(const s16x8*)((bV) + row_ * 64 + ((ks * 32 + fq * 8) ^ ((row_ & 7) << 3))); \
      _Pragma("unroll") \
      for (int mi = 0; mi < 2; ++mi) \
        o[mi][nj] = __builtin_amdgcn_mfma_f32_16x16x32_bf16(pf[mi], vf, o[mi][nj], 0, 0, 0); \
    } \
  } \
} while (0)

__global__ __launch_bounds__(512, 2) void attn_kernel(const bf16* __restrict__ Q,
                                                      const bf16* __restrict__ K,
                                                      const bf16* __restrict__ Vt,
                                                      bf16* __restrict__ AO) {
  __shared__ alignas(16) bf16 lds[49152];   // 96 KiB: KV dbuf 64 + sP 32
  bf16* const ldsK0 = lds;                  // [64][128]
  bf16* const ldsV0 = lds + 8192;           // [128][64]
  bf16* const ldsK1 = lds + 16384;
  bf16* const ldsV1 = lds + 24576;
  bf16* const sP    = lds + 32768;          // 8 waves x [32][64]
  const int tid = threadIdx.x;
  const int w = tid >> 6, ln = tid & 63;
  const int fr = ln & 15, fq = ln >> 4;
  const int lg = (blockIdx.x & 7) * 64 + (blockIdx.x >> 3);   // same-bh pair on same XCD
  const int bh = lg >> 1;
  const int q0 = (lg & 1) * 256;
  const long base = (long)bh << 16;         // bh * 512 * 128
  bf16* const sPw = sP + w * 2048;

  // thread-constant staging source bases (inverse-swizzled global addresses)
  const int kr0 = tid >> 4, kc = tid & 15;          // K/Q chunk coords (rows 0..31)
  const int vr0 = tid >> 3, vc = tid & 7;           // V^T chunk coords (rows 0..63)
  const bf16* const kgb = K + base + kr0 * 128 + ((kc ^ (kr0 & 7)) * 8);
  const bf16* const vgb = Vt + base + (long)vr0 * 512 + ((vc ^ (vr0 & 7)) * 8);

  // --- stage Q tile (256x128) swizzled into lds[0..32767], read fragments
  {
    const bf16* const qgb = Q + base + (long)q0 * 128 + kr0 * 128 + ((kc ^ (kr0 & 7)) * 8);
#pragma unroll
    for (int p = 0; p < 8; ++p)
      gll16(qgb + p * 4096, lds + tid * 8 + p * 4096);
  }
  __syncthreads();   // drains vmcnt(0): Q landed for all waves
  s16x8 qf[2][4];
#pragma unroll
  for (int mi = 0; mi < 2; ++mi) {
    const int row = w * 32 + mi * 16 + fr;
#pragma unroll
    for (int ks = 0; ks < 4; ++ks)
      qf[mi][ks] = *(const s16x8*)(lds + row * 128 + ((ks * 32 + fq * 8) ^ ((row & 7) << 3)));
  }
  __syncthreads();   // drains lgkm: Q region free for tile0

  f32x4 o[2][8] = {};
  float lrow[2][4] = {};

  STAGE(0, ldsK0, ldsV0);
  STAGE(1, ldsK1, ldsV1);

  for (int kt = 0; kt < 7; ++kt) {
    const bf16* bK = (kt & 1) ? ldsK1 : ldsK0;
    const bf16* bV = (kt & 1) ? ldsV1 : ldsV0;
    asm volatile("s_waitcnt vmcnt(4)" ::: "memory");   // tile kt landed; kt+1 in flight
    __builtin_amdgcn_sched_barrier(0);
    __builtin_amdgcn_s_barrier();
    COMPUTE(bK, bV);
    asm volatile("s_waitcnt lgkmcnt(0)" ::: "memory"); // my LDS reads complete
    __builtin_amdgcn_sched_barrier(0);
    __builtin_amdgcn_s_barrier();                      // everyone done reading buf
    if (kt < 6) STAGE(kt + 2, (bf16*)bK, (bf16*)bV);   // overwrite current buf
  }
  asm volatile("s_waitcnt vmcnt(0)" ::: "memory");
  __builtin_amdgcn_sched_barrier(0);
  __builtin_amdgcn_s_barrier();
  COMPUTE(ldsK1, ldsV1);   // kt = 7

  // epilogue: O /= l, write AO[b][t][h*128 + d]
  const int b = bh >> 3, h = bh & 7;
  float rl[2][4];
#pragma unroll
  for (int mi = 0; mi < 2; ++mi)
#pragma unroll
    for (int r = 0; r < 4; ++r) rl[mi][r] = 1.f / lrow[mi][r];
#pragma unroll
  for (int mi = 0; mi < 2; ++mi)
#pragma unroll
    for (int nj = 0; nj < 8; ++nj) {
      const int col = h * 128 + nj * 16 + fr;
#pragma unroll
      for (int r = 0; r < 4; ++r) {
        const int trow = q0 + w * 32 + mi * 16 + fq * 4 + r;
        AO[((long)(b * 512 + trow) << 10) + col] = __float2bfloat16(o[mi][nj][r] * rl[mi][r]);
      }
    }
}

// ---------------- launch ----------------
extern "C" void kernel_launch(void* const* d_in, const int* in_sizes, int n_in,
                              void* d_out, int out_size, void* d_ws, size_t ws_size,
                              hipStream_t stream) {
  const float* xf = (const float*)d_in[0];
  const float* xs = (const float*)d_in[1];
  // weight order in WW: 0=wq1,1=wk1,2=wv1,3=wq2,4=wk2,5=wv2,6=wo1,7=wo2
  const float* w_f[8] = { (const float*)d_in[2], (const float*)d_in[4], (const float*)d_in[6],
                          (const float*)d_in[8], (const float*)d_in[10], (const float*)d_in[12],
                          (const float*)d_in[14], (const float*)d_in[16] };

  bf16* ws = (bf16*)d_ws;
  bf16* XF = ws;                       // 8,388,608 bf16
  bf16* XS = ws + 8388608;             // 8,388,608
  bf16* WW = ws + 16777216;            // 8 x 262,144
  bf16* Qb = ws + 18874368;            // 16,777,216 each
  bf16* Kb = Qb + 16777216;
  bf16* Vb = Kb + 16777216;            // V^T layout (bh, d, t)
  bf16* AO = ws;                       // reuse XF+XS region

  ConvParams cp;
  cp.j[0] = { xf, XF, 2097152, 0 };
  cp.j[1] = { xs, XS, 2097152, 0 };
  for (int i = 0; i < 8; ++i) cp.j[2 + i] = { w_f[i], WW + i * 262144, 65536, 0 };
  convert_kernel<<<dim3(512, 1, 10), 256, 0, stream>>>(cp);

  const float qsc = 0.125f * 1.44269504088896f;   // fold log2(e) so attn uses exp2
  GemmParams gp;
  gp.s[0] = { XF, WW + 0 * 262144, (const float*)d_in[3],  Qb, nullptr, 512, 0,  qsc, 0 };
  gp.s[1] = { XS, WW + 3 * 262144, (const float*)d_in[9],  Qb, nullptr, 512, 64, qsc, 0 };
  gp.s[2] = { XF, WW + 1 * 262144, (const float*)d_in[5],  Kb, nullptr, 512, 0,  1.f, 0 };
  gp.s[3] = { XS, WW + 4 * 262144, (const float*)d_in[11], Kb, nullptr, 512, 64, 1.f, 0 };
  gp.s[4] = { XF, WW + 2 * 262144, (const float*)d_in[7],  Vb, nullptr, 512, 0,  1.f, 2 };
  gp.s[5] = { XS, WW + 5 * 262144, (const float*)d_in[13], Vb, nullptr, 512, 64, 1.f, 2 };
  gemm_kernel<<<dim3(128, 4, 6), 256, 0, stream>>>(gp);

  attn_kernel<<<dim3(512), 512, 0, stream>>>(Qb, Kb, Vb, AO);

  float* out = (float*)d_out;
  GemmParams op;
  op.s[0] = { AO,       WW + 6 * 262144, (const float*)d_in[15], nullptr, out,           1024, 0, 1.f, 1 };
  op.s[1] = { AO + 512, WW + 7 * 262144, (const float*)d_in[17], nullptr, out + 8388608, 1024, 0, 1.f, 1 };
  op.s[2] = op.s[0]; op.s[3] = op.s[0]; op.s[4] = op.s[0]; op.s[5] = op.s[0];
  gemm_kernel<<<dim3(128, 4, 2), 256, 0, stream>>>(op);
}